// Round 7
// baseline (504.893 us; speedup 1.0000x reference)
//
#include <hip/hip_runtime.h>
#include <hip/hip_bf16.h>
#include <cstdint>
#include <cstddef>

typedef __bf16 bf8_t __attribute__((ext_vector_type(8)));
typedef __bf16 bf4_t __attribute__((ext_vector_type(4)));
typedef float  f4_t  __attribute__((ext_vector_type(4)));

#define CC 768
#define NROWS 32768           // 8*4096
#define NTOT 25165824         // 32768*768

__device__ __forceinline__ void gld16(const void* g, void* l) {
  __builtin_amdgcn_global_load_lds(
      (const __attribute__((address_space(1))) void*)g,
      (__attribute__((address_space(3))) void*)l, 16, 0, 0);
}

// ---------------- prep kernels ----------------

__global__ void make_cas(__bf16* __restrict__ cas) {
  int idx = blockIdx.x * 256 + threadIdx.x;      // 589824 total
  int i = idx / CC, j = idx - i * CC;
  int ij = (i * j) % CC;                          // exact arg reduction
  float ang = 6.283185307179586f * (float)ij / (float)CC;
  cas[idx] = (__bf16)(__cosf(ang) + __sinf(ang));
}

__global__ void cvt4(const float* __restrict__ x, __bf16* __restrict__ o) {
  int i = (blockIdx.x * 256 + threadIdx.x) * 4;
  float4 v = *(const float4*)(x + i);
  bf4_t r;
  r[0] = (__bf16)v.x; r[1] = (__bf16)v.y; r[2] = (__bf16)v.z; r[3] = (__bf16)v.w;
  *(bf4_t*)(o + i) = r;
}

// pack weights into MFMA B-fragment order: frag[(kt*12+nt)*64 + lane][j]
// B-frag semantics: lane holds B[k = kt*32 + (lane>>4)*8 + j][n = nt*16 + (lane&15)]
__global__ void pack_w1(const float* __restrict__ w1, __bf16* __restrict__ w1f) {
  int f = blockIdx.x * 256 + threadIdx.x;        // < 8*36*64*8 = 147456
  int j = f & 7, lane = (f >> 3) & 63, rest = f >> 9;
  int nt = rest % 12, kt = (rest / 12) % 3, blk = rest / 36;
  int k = kt * 32 + (lane >> 4) * 8 + j;          // 0..95  (input)
  int o = nt * 16 + (lane & 15);                  // 0..191 (output: [real|imag])
  float v = (o < 96) ? w1[(0 * 8 + blk) * 9216 + k * 96 + o]
                     : w1[(1 * 8 + blk) * 9216 + k * 96 + (o - 96)];
  w1f[f] = (__bf16)v;
}

__global__ void pack_w2(const float* __restrict__ w2, __bf16* __restrict__ w2f) {
  int f = blockIdx.x * 256 + threadIdx.x;        // < 8*72*64*8 = 294912
  int j = f & 7, lane = (f >> 3) & 63, rest = f >> 9;
  int nt = rest % 12, kt = (rest / 12) % 6, blk = rest / 72;
  int i = kt * 32 + (lane >> 4) * 8 + j;          // 0..191 (hidden: [ar|ai])
  int o = nt * 16 + (lane & 15);                  // 0..191 (out: [yr|yi])
  float v;
  if (o < 96) v = (i < 96) ?  w2[(0 * 8 + blk) * 9216 + i * 96 + o]
                           : -w2[(1 * 8 + blk) * 9216 + (i - 96) * 96 + o];
  else        v = (i < 96) ?  w2[(1 * 8 + blk) * 9216 + i * 96 + (o - 96)]
                           :  w2[(0 * 8 + blk) * 9216 + (i - 96) * 96 + (o - 96)];
  w2f[f] = (__bf16)v;
}

// ---------------- back GEMM v2 (round-3 validated form, ~58 us; setprio reverted) -------
__global__ __launch_bounds__(256, 2) void gemm_back(
    const __bf16* __restrict__ Zb, const __bf16* __restrict__ BT,
    float* __restrict__ Cf, const float* __restrict__ Xres, float scale)
{
  __shared__ __align__(16) char smem[49152];     // 3 x (sA 8KB | sB 8KB)
  const int t = threadIdx.x;
  const int lane = t & 63, wid = t >> 6;
  const int wm = (wid >> 1) * 64, wn = (wid & 1) * 64;

  const int id = blockIdx.x;
  const int sid = (id & 7) * 192 + (id >> 3);
  const int m0 = (sid / 6) * 128, n0 = (sid % 6) * 128;

  const int q = lane >> 4, r = lane & 15;
  const __bf16* gA = Zb + (size_t)(m0 + (t >> 2)) * CC + (t & 3) * 8;
  const __bf16* gB = BT + (size_t)(n0 + (t >> 2)) * CC + (t & 3) * 8;
  const int ldsOff = (t >> 2) * 32 + (t & 3) * 8;  // byte off = t*16 (lane-linear)

  auto stage = [&](int b, int tile) {
    int k0 = tile * 32;
    __bf16* lA = (__bf16*)(smem + b * 16384) + ldsOff;
    __bf16* lB = (__bf16*)(smem + b * 16384 + 8192) + ldsOff;
    gld16(gA + k0, lA);
    gld16(gA + (size_t)64 * CC + k0, lA + 64 * 32);
    gld16(gB + k0, lB);
    gld16(gB + (size_t)64 * CC + k0, lB + 64 * 32);
  };

  f4_t acc[4][4] = {};
  stage(0, 0);
  stage(1, 1);
  for (int tile = 0; tile < 24; ++tile) {
    int nt = tile + 2; if (nt > 23) nt = 23;       // clamped duplicate in tail
    stage((tile + 2) % 3, nt);
    asm volatile("s_waitcnt vmcnt(8)" ::: "memory");   // tile `tile` complete
    __builtin_amdgcn_s_barrier();
    const __bf16* sA = (const __bf16*)(smem + (tile % 3) * 16384);
    const __bf16* sB = sA + 8192 / 2;
    bf8_t af[4], bfr[4];
#pragma unroll
    for (int i = 0; i < 4; i++)
      af[i] = *(const bf8_t*)(sA + (wm + i * 16 + r) * 32 + q * 8);
#pragma unroll
    for (int j = 0; j < 4; j++)
      bfr[j] = *(const bf8_t*)(sB + (wn + j * 16 + r) * 32 + q * 8);
#pragma unroll
    for (int i = 0; i < 4; i++)
#pragma unroll
      for (int j = 0; j < 4; j++)
        acc[i][j] = __builtin_amdgcn_mfma_f32_16x16x32_bf16(af[i], bfr[j], acc[i][j], 0, 0, 0);
    __builtin_amdgcn_s_barrier();   // all waves done with buf[tile%3] before restage
  }

  // ---- epilogue: LDS-staged coalesced f32 writeback, two 64-row halves ----
  float* cs = (float*)smem;                        // 64 x 132 f32 = 33 KB < 48 KB
#pragma unroll
  for (int h = 0; h < 2; ++h) {
    __builtin_amdgcn_s_barrier();                  // prev half's copy-out done
    if ((wid >> 1) == h) {
#pragma unroll
      for (int i = 0; i < 4; i++)
#pragma unroll
        for (int j = 0; j < 4; j++)
#pragma unroll
          for (int rr = 0; rr < 4; rr++)
            cs[(i * 16 + q * 4 + rr) * 132 + wn + j * 16 + r] = acc[i][j][rr];
    }
    __builtin_amdgcn_s_barrier();
    const int u = t & 31, row8 = t >> 5;
#pragma unroll
    for (int p = 0; p < 8; ++p) {
      int rl = p * 8 + row8;
      size_t goff = (size_t)(m0 + h * 64 + rl) * CC + n0 + u * 4;
      f4_t xr = *(const f4_t*)(Xres + goff);
      f4_t cv = *(const f4_t*)(cs + rl * 132 + u * 4);
      f4_t o;
      o[0] = cv[0] * scale + xr[0];
      o[1] = cv[1] * scale + xr[1];
      o[2] = cv[2] * scale + xr[2];
      o[3] = cv[3] * scale + xr[3];
      *(f4_t*)(Cf + goff) = o;
    }
  }
}

// ---------------- fused6: 3-blocks/CU via B-from-L2 + 51.2 KB LDS ------------------------
// Round-7 changes vs fused3 (validated 116 us): (a) T5 setprio reverted (round-6: -20%).
// (b) B (CAS) is no longer LDS-staged: CAS is symmetric and L2-resident, so the MFMA
// B-fragment is a contiguous 16B global load CAS[n0+w*32+j*16+r][k0+q*8] -- ping-pong
// double-buffered in registers, issued one K-step early (L2 latency hidden under MFMA).
// Staging shrinks to 3 x 8 KB (A only). (c) vt becomes per-cb 64x104 written by the 3
// owning waves per (h,cb). MLP peak LDS = Hs 25.6K + vt 13K + zl 12.3K = 51.2 KB
// -> 3 blocks/CU (was 2): +50% TLP for a latency-bound kernel.
// vmcnt (FIFO-verified, uniform incl. tail via clamped dummy stage/loadB):
// waves 0-1 stage 2 A-loads -> wait vmcnt(4); waves 2-5 stage 1 -> vmcnt(3).
__global__ __launch_bounds__(384, 4) void fused6(
    const __bf16* __restrict__ A, const __bf16* __restrict__ BT,
    const __bf16* __restrict__ w1f, const __bf16* __restrict__ w2f,
    const float* __restrict__ b1, const float* __restrict__ b2,
    __bf16* __restrict__ Z)
{
  __shared__ __align__(16) char smem[51200];
  __bf16* Hs = (__bf16*)smem;                      // [0,25600)      (aliases 3x8K staging)
  __bf16* vt = (__bf16*)(smem + 25600);            // [25600,38912)  64 x 104
  __bf16* zl = (__bf16*)(smem + 38912);            // [38912,51200)  64 x 96

  const int t = threadIdx.x, lane = t & 63, w = t >> 6;   // w in 0..5
  const int id = blockIdx.x;
  const int sid = (id & 7) * 128 + (id >> 3);             // bijective XCD swizzle
  const int cbp = sid & 3;                 // channel-block pair 0..3
  const int m0 = (sid >> 2) * 128;         // row tile
  const int n0 = cbp * 192;
  const int q = lane >> 4, r = lane & 15;

  // ---- K-loop: V[128x192] = A[m0:m0+128,:] @ CAS[:, n0:n0+192] ----
  const __bf16* gA  = A  + (size_t)(m0 + (t >> 2)) * CC + (t & 3) * 8;
  const __bf16* gA2 = A  + (size_t)(m0 + 96 + (t >> 2)) * CC + (t & 3) * 8;   // t<128
  const __bf16* gBf = BT + (size_t)(n0 + w * 32 + r) * CC + q * 8;            // B frag base

  auto stageA = [&](int b, int tile) {
    int k0 = tile * 32;
    char* base = smem + b * 8192;
    gld16(gA + k0, (__bf16*)base + t * 8);
    if (t < 128) gld16(gA2 + k0, (__bf16*)base + (384 + t) * 8);   // waves 0,1 only
  };
  auto loadB = [&](bf8_t* dst, int tile) {
    int k0 = tile * 32;
    dst[0] = *(const bf8_t*)(gBf + k0);
    dst[1] = *(const bf8_t*)(gBf + (size_t)16 * CC + k0);
  };

  f4_t acc[8][2] = {};
  bf8_t bP[2], bQ[2];                              // ping-pong B fragments
  stageA(0, 0);
  stageA(1, 1);
  loadB(bP, 0);

#define FUSED6_STEP(TILE, STG_T, BNEXT_T, BDST, BUSE)                          \
  {                                                                            \
    stageA(((TILE) + 2) % 3, (STG_T));                                         \
    loadB((BDST), (BNEXT_T));                                                  \
    if (w < 2) asm volatile("s_waitcnt vmcnt(4)" ::: "memory");                \
    else       asm volatile("s_waitcnt vmcnt(3)" ::: "memory");                \
    __builtin_amdgcn_s_barrier();                                              \
    const __bf16* sA = (const __bf16*)(smem + ((TILE) % 3) * 8192);            \
    bf8_t af[8];                                                               \
    _Pragma("unroll")                                                          \
    for (int i = 0; i < 8; i++)                                                \
      af[i] = *(const bf8_t*)(sA + (i * 16 + r) * 32 + q * 8);                 \
    _Pragma("unroll")                                                          \
    for (int i = 0; i < 8; i++)                                                \
      _Pragma("unroll")                                                        \
      for (int j = 0; j < 2; j++)                                              \
        acc[i][j] = __builtin_amdgcn_mfma_f32_16x16x32_bf16(af[i], (BUSE)[j],  \
                                                            acc[i][j], 0, 0, 0);\
    __builtin_amdgcn_s_barrier();                                              \
  }

  for (int u = 0; u < 24; u += 2) {
    int s2 = u + 2; if (s2 > 23) s2 = 23;          // clamped duplicates in tail
    int s3 = u + 3; if (s3 > 23) s3 = 23;
    int bn1 = u + 1;                               // < 24 always
    int bn2 = u + 2; if (bn2 > 23) bn2 = 23;       // dummy at the end (uniform vmcnt)
    FUSED6_STEP(u,     s2, bn1, bQ, bP)            // compute tile u   with bP
    FUSED6_STEP(u + 1, s3, bn2, bP, bQ)            // compute tile u+1 with bQ
  }
#undef FUSED6_STEP

  // drain duplicate tail stages before Hs (aliases staging buffers)
  asm volatile("s_waitcnt vmcnt(0)" ::: "memory");
  __builtin_amdgcn_s_barrier();

  // ---- two 64-row half-passes; per (h,cb): vtW -> P1 -> P2 -> copy-out ----
#pragma unroll
  for (int h = 0; h < 2; h++) {
#pragma unroll
    for (int cb = 0; cb < 2; cb++) {
      // vt write: the 3 waves owning cols [cb*96, cb*96+96)   (wave w -> cols w*32..+32)
      if ((w / 3) == cb) {
        const int wl = w - cb * 3;                 // 0..2
#pragma unroll
        for (int ii = 0; ii < 4; ii++)
#pragma unroll
          for (int j = 0; j < 2; j++) {
            int col = wl * 32 + j * 16 + r;
#pragma unroll
            for (int rr = 0; rr < 4; rr++) {
              int row = ii * 16 + q * 4 + rr;
              vt[row * 104 + col] = (__bf16)acc[h * 4 + ii][j][rr];
            }
          }
      }
      __syncthreads();

      const int bidx = cbp * 2 + cb;
      const __bf16* w1b = w1f + (size_t)bidx * (36 * 64 * 8);
      const __bf16* w2b = w2f + (size_t)bidx * (72 * 64 * 8);
      bf8_t w1r[3][2], w2r[6][2];
#pragma unroll
      for (int kt = 0; kt < 3; kt++)
#pragma unroll
        for (int j = 0; j < 2; j++)
          w1r[kt][j] = *(const bf8_t*)(w1b + ((size_t)(kt * 12 + 2 * w + j) * 64 + lane) * 8);
#pragma unroll
      for (int kt = 0; kt < 6; kt++) {
        w2r[kt][0] = *(const bf8_t*)(w2b + ((size_t)(kt * 12 + w) * 64 + lane) * 8);
        w2r[kt][1] = *(const bf8_t*)(w2b + ((size_t)(kt * 12 + w + 6) * 64 + lane) * 8);
      }
      float bb[2];
#pragma unroll
      for (int j = 0; j < 2; j++) {
        int c = (2 * w + j) * 16 + r;
        bb[j] = (c < 96) ? b1[bidx * 96 + c] : b1[768 + bidx * 96 + (c - 96)];
      }
      const float br = b2[bidx * 96 + w * 16 + r];
      const float bi = b2[768 + bidx * 96 + w * 16 + r];

      // phase 1: Hs[64][192] = relu(vt W1 + b1), wave w writes cols [32w,32w+32)
#pragma unroll
      for (int rt = 0; rt < 4; rt++) {
        const __bf16* vp = vt + (rt * 16 + r) * 104 + q * 8;
        f4_t a0 = {}, a1 = {};
#pragma unroll
        for (int kt = 0; kt < 3; kt++) {
          bf8_t a = *(const bf8_t*)(vp + kt * 32);
          a0 = __builtin_amdgcn_mfma_f32_16x16x32_bf16(a, w1r[kt][0], a0, 0, 0, 0);
          a1 = __builtin_amdgcn_mfma_f32_16x16x32_bf16(a, w1r[kt][1], a1, 0, 0, 0);
        }
#pragma unroll
        for (int j = 0; j < 2; j++) {
          int c = (2 * w + j) * 16 + r;
          f4_t* ap = j ? &a1 : &a0;
#pragma unroll
          for (int rr = 0; rr < 4; rr++) {
            float v = (*ap)[rr] + bb[j];
            Hs[(rt * 16 + q * 4 + rr) * 200 + c] = (__bf16)(v > 0.f ? v : 0.f);
          }
        }
      }
      __syncthreads();
      // phase 2: y = Hs W2pack + b2; z = ss(yr)-ss(yi); wave w -> z cols [16w,16w+16)
#pragma unroll
      for (int rt = 0; rt < 4; rt++) {
        f4_t ar = {}, ai = {};
#pragma unroll
        for (int kt = 0; kt < 6; kt++) {
          bf8_t a = *(const bf8_t*)(&Hs[(rt * 16 + r) * 200 + kt * 32 + q * 8]);
          ar = __builtin_amdgcn_mfma_f32_16x16x32_bf16(a, w2r[kt][0], ar, 0, 0, 0);
          ai = __builtin_amdgcn_mfma_f32_16x16x32_bf16(a, w2r[kt][1], ai, 0, 0, 0);
        }
#pragma unroll
        for (int rr = 0; rr < 4; rr++) {
          float yr = ar[rr] + br, yi = ai[rr] + bi;
          float sr = fabsf(yr) - 0.01f; sr = sr > 0.f ? copysignf(sr, yr) : 0.f;
          float si = fabsf(yi) - 0.01f; si = si > 0.f ? copysignf(si, yi) : 0.f;
          zl[(rt * 16 + q * 4 + rr) * 96 + w * 16 + r] = (__bf16)(sr - si);
        }
      }
      __syncthreads();
      // copy-out: 64 rows x 48 dwords, coalesced. No trailing barrier needed: the next
      // zl write (next cb's phase 2) is separated by this cb's vtW->P1 and P1->P2 syncs.
      {
        const uint32_t* zsrc = (const uint32_t*)zl;
        int cdw = t % 48, crow = t / 48;
        int rbase = m0 + h * 64;
#pragma unroll
        for (int it = 0; it < 8; it++) {
          int row = it * 8 + crow;
          uint32_t* dst = (uint32_t*)(Z + (size_t)(rbase + row) * CC + n0 + cb * 96);
          dst[cdw] = zsrc[row * 48 + cdw];
        }
      }
    }
  }
}

// ---------------- launch ----------------

extern "C" void kernel_launch(void* const* d_in, const int* in_sizes, int n_in,
                              void* d_out, int out_size, void* d_ws, size_t ws_size,
                              hipStream_t stream) {
  const float* x  = (const float*)d_in[0];
  const float* w1 = (const float*)d_in[1];
  const float* b1 = (const float*)d_in[2];
  const float* w2 = (const float*)d_in[3];
  const float* b2 = (const float*)d_in[4];
  float* out = (float*)d_out;

  char* ws = (char*)d_ws;
  size_t off = 0;
  auto alloc = [&](size_t bytes) {
    char* p = ws + off;
    off += (bytes + 255) & ~(size_t)255;
    return p;
  };
  __bf16* casb = (__bf16*)alloc((size_t)CC * CC * 2);        // 1.18 MB
  __bf16* w1f  = (__bf16*)alloc((size_t)8 * 36 * 64 * 8 * 2);
  __bf16* w2f  = (__bf16*)alloc((size_t)8 * 72 * 64 * 8 * 2);
  __bf16* xb   = (__bf16*)alloc((size_t)NTOT * 2);           // 50.3 MB
  __bf16* vv   = (__bf16*)alloc((size_t)NTOT * 2);           // 50.3 MB (Z)

  make_cas<<<2304, 256, 0, stream>>>(casb);
  cvt4<<<24576, 256, 0, stream>>>(x, xb);
  pack_w1<<<576, 256, 0, stream>>>(w1, w1f);
  pack_w2<<<1152, 256, 0, stream>>>(w2, w2f);

  // Z = softshrink-MLP(Xbf16 @ CAS), fused per (row-tile, channel-block-pair)
  fused6<<<1024, 384, 0, stream>>>(xb, casb, w1f, w2f, b1, b2, vv);
  // OUT = Z @ CAS / n_tot + X  (counted-vmcnt pipeline + coalesced epilogue)
  gemm_back<<<1536, 256, 0, stream>>>(vv, casb, out, x, 1.0f / 25165824.0f);
}

// Round 8
// 335.078 us; speedup vs baseline: 1.5068x; 1.5068x over previous
//
#include <hip/hip_runtime.h>
#include <hip/hip_bf16.h>
#include <cstdint>
#include <cstddef>

typedef __bf16 bf8_t __attribute__((ext_vector_type(8)));
typedef __bf16 bf4_t __attribute__((ext_vector_type(4)));
typedef float  f4_t  __attribute__((ext_vector_type(4)));

#define CC 768
#define NROWS 32768           // 8*4096
#define NTOT 25165824         // 32768*768

__device__ __forceinline__ void gld16(const void* g, void* l) {
  __builtin_amdgcn_global_load_lds(
      (const __attribute__((address_space(1))) void*)g,
      (__attribute__((address_space(3))) void*)l, 16, 0, 0);
}

// ---------------- merged prep: cvt4 | make_cas | pack_w1 | pack_w2 ----------------------
// One dispatch, partitioned by blockIdx (all four are independent elementwise ops; the
// small ops overlap cvt4's memory phase instead of serializing as 4 launches).
__global__ void prep_all(const float* __restrict__ x, __bf16* __restrict__ xb,
                         __bf16* __restrict__ cas,
                         const float* __restrict__ w1, __bf16* __restrict__ w1f,
                         const float* __restrict__ w2, __bf16* __restrict__ w2f)
{
  const int b = blockIdx.x;
  if (b < 24576) {
    // cvt4: x f32 -> bf16, 4/thread
    int i = (b * 256 + threadIdx.x) * 4;
    float4 v = *(const float4*)(x + i);
    bf4_t rv;
    rv[0] = (__bf16)v.x; rv[1] = (__bf16)v.y; rv[2] = (__bf16)v.z; rv[3] = (__bf16)v.w;
    *(bf4_t*)(xb + i) = rv;
  } else if (b < 26880) {
    // make_cas: 589824 elems
    int idx = (b - 24576) * 256 + threadIdx.x;
    int i = idx / CC, j = idx - i * CC;
    int ij = (i * j) % CC;                        // exact arg reduction
    float ang = 6.283185307179586f * (float)ij / (float)CC;
    cas[idx] = (__bf16)(__cosf(ang) + __sinf(ang));
  } else if (b < 27456) {
    // pack_w1: MFMA B-frag order frag[(kt*12+nt)*64+lane][j]
    int f = (b - 26880) * 256 + threadIdx.x;      // < 147456
    int j = f & 7, lane = (f >> 3) & 63, rest = f >> 9;
    int nt = rest % 12, kt = (rest / 12) % 3, blk = rest / 36;
    int k = kt * 32 + (lane >> 4) * 8 + j;        // 0..95
    int o = nt * 16 + (lane & 15);                // 0..191 ([real|imag])
    float v = (o < 96) ? w1[(0 * 8 + blk) * 9216 + k * 96 + o]
                       : w1[(1 * 8 + blk) * 9216 + k * 96 + (o - 96)];
    w1f[f] = (__bf16)v;
  } else {
    // pack_w2
    int f = (b - 27456) * 256 + threadIdx.x;      // < 294912
    int j = f & 7, lane = (f >> 3) & 63, rest = f >> 9;
    int nt = rest % 12, kt = (rest / 12) % 6, blk = rest / 72;
    int i = kt * 32 + (lane >> 4) * 8 + j;        // 0..191 ([ar|ai])
    int o = nt * 16 + (lane & 15);                // 0..191 ([yr|yi])
    float v;
    if (o < 96) v = (i < 96) ?  w2[(0 * 8 + blk) * 9216 + i * 96 + o]
                             : -w2[(1 * 8 + blk) * 9216 + (i - 96) * 96 + o];
    else        v = (i < 96) ?  w2[(1 * 8 + blk) * 9216 + i * 96 + (o - 96)]
                             :  w2[(0 * 8 + blk) * 9216 + (i - 96) * 96 + (o - 96)];
    w2f[f] = (__bf16)v;
  }
}

// ---------------- back GEMM (round-3 validated, ~58 us) ---------------------------------
// counted-vmcnt 3-buffer pipeline + LDS-staged coalesced epilogue.
// __launch_bounds__(256,3): LDS 48K allows exactly 3 blocks/CU; bound keeps the
// allocator under the 3-wave/EU VGPR cap (~168; actual ~80-110 — no spill risk).
__global__ __launch_bounds__(256, 3) void gemm_back(
    const __bf16* __restrict__ Zb, const __bf16* __restrict__ BT,
    float* __restrict__ Cf, const float* __restrict__ Xres, float scale)
{
  __shared__ __align__(16) char smem[49152];     // 3 x (sA 8KB | sB 8KB)
  const int t = threadIdx.x;
  const int lane = t & 63, wid = t >> 6;
  const int wm = (wid >> 1) * 64, wn = (wid & 1) * 64;

  const int id = blockIdx.x;
  const int sid = (id & 7) * 192 + (id >> 3);     // bijective XCD chunking (1536%8==0)
  const int m0 = (sid / 6) * 128, n0 = (sid % 6) * 128;

  const int q = lane >> 4, r = lane & 15;
  const __bf16* gA = Zb + (size_t)(m0 + (t >> 2)) * CC + (t & 3) * 8;
  const __bf16* gB = BT + (size_t)(n0 + (t >> 2)) * CC + (t & 3) * 8;
  const int ldsOff = (t >> 2) * 32 + (t & 3) * 8;  // byte off = t*16 (lane-linear)

  auto stage = [&](int b, int tile) {
    int k0 = tile * 32;
    __bf16* lA = (__bf16*)(smem + b * 16384) + ldsOff;
    __bf16* lB = (__bf16*)(smem + b * 16384 + 8192) + ldsOff;
    gld16(gA + k0, lA);
    gld16(gA + (size_t)64 * CC + k0, lA + 64 * 32);
    gld16(gB + k0, lB);
    gld16(gB + (size_t)64 * CC + k0, lB + 64 * 32);
  };

  f4_t acc[4][4] = {};
  stage(0, 0);
  stage(1, 1);
  for (int tile = 0; tile < 24; ++tile) {
    int nt = tile + 2; if (nt > 23) nt = 23;       // clamped duplicate in tail
    stage((tile + 2) % 3, nt);
    asm volatile("s_waitcnt vmcnt(8)" ::: "memory");   // tile `tile` complete
    __builtin_amdgcn_s_barrier();
    const __bf16* sA = (const __bf16*)(smem + (tile % 3) * 16384);
    const __bf16* sB = sA + 8192 / 2;
    bf8_t af[4], bfr[4];
#pragma unroll
    for (int i = 0; i < 4; i++)
      af[i] = *(const bf8_t*)(sA + (wm + i * 16 + r) * 32 + q * 8);
#pragma unroll
    for (int j = 0; j < 4; j++)
      bfr[j] = *(const bf8_t*)(sB + (wn + j * 16 + r) * 32 + q * 8);
#pragma unroll
    for (int i = 0; i < 4; i++)
#pragma unroll
      for (int j = 0; j < 4; j++)
        acc[i][j] = __builtin_amdgcn_mfma_f32_16x16x32_bf16(af[i], bfr[j], acc[i][j], 0, 0, 0);
    __builtin_amdgcn_s_barrier();   // all waves done with buf[tile%3] before restage
  }

  // ---- epilogue: LDS-staged coalesced f32 writeback, two 64-row halves ----
  float* cs = (float*)smem;                        // 64 x 132 f32 = 33 KB < 48 KB
#pragma unroll
  for (int h = 0; h < 2; ++h) {
    __builtin_amdgcn_s_barrier();                  // prev half's copy-out done
    if ((wid >> 1) == h) {
#pragma unroll
      for (int i = 0; i < 4; i++)
#pragma unroll
        for (int j = 0; j < 4; j++)
#pragma unroll
          for (int rr = 0; rr < 4; rr++)
            cs[(i * 16 + q * 4 + rr) * 132 + wn + j * 16 + r] = acc[i][j][rr];
    }
    __builtin_amdgcn_s_barrier();
    const int u = t & 31, row8 = t >> 5;
#pragma unroll
    for (int p = 0; p < 8; ++p) {
      int rl = p * 8 + row8;
      size_t goff = (size_t)(m0 + h * 64 + rl) * CC + n0 + u * 4;
      f4_t xr = *(const f4_t*)(Xres + goff);
      f4_t cv = *(const f4_t*)(cs + rl * 132 + u * 4);
      f4_t o;
      o[0] = cv[0] * scale + xr[0];
      o[1] = cv[1] * scale + xr[1];
      o[2] = cv[2] * scale + xr[2];
      o[3] = cv[3] * scale + xr[3];
      *(f4_t*)(Cf + goff) = o;
    }
  }
}

// ---------------- fused3 (round-4 validated, 116.3 us) — restored byte-identical --------
// 3-buffer counted-vmcnt K-loop (2 stages in flight, vmcnt(8/6)) + 2x block-diag MLP.
// Round-7 lessons: B stays LDS-staged (per-lane global B-frags are uncoalesced);
// no launch-bounds tightening (384,4 strangled VGPRs -> 300MB scratch).
__global__ __launch_bounds__(384, 3) void fused3(
    const __bf16* __restrict__ A, const __bf16* __restrict__ BT,
    const __bf16* __restrict__ w1f, const __bf16* __restrict__ w2f,
    const float* __restrict__ b1, const float* __restrict__ b2,
    __bf16* __restrict__ Z)
{
  __shared__ __align__(16) char smem[63488];
  __bf16* Hs = (__bf16*)smem;                      // [0,25600)
  __bf16* vt = (__bf16*)(smem + 25600);            // [25600,51200)
  __bf16* zl = (__bf16*)(smem + 51200);            // [51200,63488)

  const int t = threadIdx.x, lane = t & 63, w = t >> 6;   // w in 0..5
  const int id = blockIdx.x;
  const int sid = (id & 7) * 128 + (id >> 3);             // bijective XCD swizzle
  const int cbp = sid & 3;                 // channel-block pair 0..3
  const int m0 = (sid >> 2) * 128;         // row tile
  const int n0 = cbp * 192;
  const int q = lane >> 4, r = lane & 15;

  // ---- K-loop: V[128x192] = A[m0:m0+128,:] @ CAS[:, n0:n0+192], 3-buffer pipeline ----
  const __bf16* gA  = A  + (size_t)(m0 + (t >> 2)) * CC + (t & 3) * 8;
  const __bf16* gA2 = A  + (size_t)(m0 + 96 + (t >> 2)) * CC + (t & 3) * 8;   // t<128
  const __bf16* gB  = BT + (size_t)(n0 + (t >> 2)) * CC + (t & 3) * 8;
  const __bf16* gB2 = BT + (size_t)(n0 + 96 + (t >> 2)) * CC + (t & 3) * 8;

  auto stage = [&](int b, int tile) {
    int k0 = tile * 32;
    char* base = smem + b * 20480;                 // A [0,8192) | B [8192,20480)
    gld16(gA + k0, (__bf16*)base + t * 8);
    if (t < 128) gld16(gA2 + k0, (__bf16*)base + (384 + t) * 8);   // waves 0,1
    gld16(gB + k0, (__bf16*)(base + 8192) + t * 8);
    gld16(gB2 + k0, (__bf16*)(base + 8192) + (384 + t) * 8);
  };

  f4_t acc[8][2] = {};
  stage(0, 0);
  stage(1, 1);
  for (int tile = 0; tile < 24; ++tile) {
    int nt = tile + 2; if (nt > 23) nt = 23;       // clamped duplicate in tail
    stage((tile + 2) % 3, nt);
    // tile's stage complete when 2 newer stages remain in flight:
    if (w < 2) asm volatile("s_waitcnt vmcnt(8)" ::: "memory");   // 4 loads/stage
    else       asm volatile("s_waitcnt vmcnt(6)" ::: "memory");   // 3 loads/stage
    __builtin_amdgcn_s_barrier();
    const __bf16* sA = (const __bf16*)(smem + (tile % 3) * 20480);
    const __bf16* sB = (const __bf16*)(smem + (tile % 3) * 20480 + 8192);
    bf8_t af[8], bfr[2];
#pragma unroll
    for (int i = 0; i < 8; i++)
      af[i] = *(const bf8_t*)(sA + (i * 16 + r) * 32 + q * 8);
#pragma unroll
    for (int j = 0; j < 2; j++)
      bfr[j] = *(const bf8_t*)(sB + (w * 32 + j * 16 + r) * 32 + q * 8);
#pragma unroll
    for (int i = 0; i < 8; i++)
#pragma unroll
      for (int j = 0; j < 2; j++)
        acc[i][j] = __builtin_amdgcn_mfma_f32_16x16x32_bf16(af[i], bfr[j], acc[i][j], 0, 0, 0);
    __builtin_amdgcn_s_barrier();   // all waves done with buf[tile%3] before restage
  }
  // drain duplicate tail stages before the MLP regions (which alias staging buffers)
  asm volatile("s_waitcnt vmcnt(0)" ::: "memory");
  __builtin_amdgcn_s_barrier();

  // ---- two 64-row half-passes (MLP body validated rounds 2-4) ----
#pragma unroll
  for (int h = 0; h < 2; h++) {
#pragma unroll
    for (int ii = 0; ii < 4; ii++)
#pragma unroll
      for (int j = 0; j < 2; j++) {
        int col = w * 32 + j * 16 + r;
#pragma unroll
        for (int rr = 0; rr < 4; rr++) {
          int row = ii * 16 + q * 4 + rr;
          vt[row * 200 + col] = (__bf16)acc[h * 4 + ii][j][rr];
        }
      }
    __syncthreads();

#pragma unroll
    for (int cb = 0; cb < 2; cb++) {
      const int bidx = cbp * 2 + cb;
      const __bf16* w1b = w1f + (size_t)bidx * (36 * 64 * 8);
      const __bf16* w2b = w2f + (size_t)bidx * (72 * 64 * 8);
      bf8_t w1r[3][2], w2r[6][2];
#pragma unroll
      for (int kt = 0; kt < 3; kt++)
#pragma unroll
        for (int j = 0; j < 2; j++)
          w1r[kt][j] = *(const bf8_t*)(w1b + ((size_t)(kt * 12 + 2 * w + j) * 64 + lane) * 8);
#pragma unroll
      for (int kt = 0; kt < 6; kt++) {
        w2r[kt][0] = *(const bf8_t*)(w2b + ((size_t)(kt * 12 + w) * 64 + lane) * 8);
        w2r[kt][1] = *(const bf8_t*)(w2b + ((size_t)(kt * 12 + w + 6) * 64 + lane) * 8);
      }
      float bb[2];
#pragma unroll
      for (int j = 0; j < 2; j++) {
        int c = (2 * w + j) * 16 + r;
        bb[j] = (c < 96) ? b1[bidx * 96 + c] : b1[768 + bidx * 96 + (c - 96)];
      }
      const float br = b2[bidx * 96 + w * 16 + r];
      const float bi = b2[768 + bidx * 96 + w * 16 + r];

      // phase 1: Hs[64][192] = relu(V[:,cb*96:+96] W1 + b1), wave w: cols [32w,32w+32)
#pragma unroll
      for (int rt = 0; rt < 4; rt++) {
        const __bf16* vp = vt + (rt * 16 + r) * 200 + cb * 96 + q * 8;
        f4_t a0 = {}, a1 = {};
#pragma unroll
        for (int kt = 0; kt < 3; kt++) {
          bf8_t a = *(const bf8_t*)(vp + kt * 32);
          a0 = __builtin_amdgcn_mfma_f32_16x16x32_bf16(a, w1r[kt][0], a0, 0, 0, 0);
          a1 = __builtin_amdgcn_mfma_f32_16x16x32_bf16(a, w1r[kt][1], a1, 0, 0, 0);
        }
#pragma unroll
        for (int j = 0; j < 2; j++) {
          int c = (2 * w + j) * 16 + r;
          f4_t* ap = j ? &a1 : &a0;
#pragma unroll
          for (int rr = 0; rr < 4; rr++) {
            float v = (*ap)[rr] + bb[j];
            Hs[(rt * 16 + q * 4 + rr) * 200 + c] = (__bf16)(v > 0.f ? v : 0.f);
          }
        }
      }
      __syncthreads();
      // phase 2: y = H W2pack + b2; z = ss(yr)-ss(yi); wave w -> z cols [16w,16w+16)
#pragma unroll
      for (int rt = 0; rt < 4; rt++) {
        f4_t ar = {}, ai = {};
#pragma unroll
        for (int kt = 0; kt < 6; kt++) {
          bf8_t a = *(const bf8_t*)(&Hs[(rt * 16 + r) * 200 + kt * 32 + q * 8]);
          ar = __builtin_amdgcn_mfma_f32_16x16x32_bf16(a, w2r[kt][0], ar, 0, 0, 0);
          ai = __builtin_amdgcn_mfma_f32_16x16x32_bf16(a, w2r[kt][1], ai, 0, 0, 0);
        }
#pragma unroll
        for (int rr = 0; rr < 4; rr++) {
          float yr = ar[rr] + br, yi = ai[rr] + bi;
          float sr = fabsf(yr) - 0.01f; sr = sr > 0.f ? copysignf(sr, yr) : 0.f;
          float si = fabsf(yi) - 0.01f; si = si > 0.f ? copysignf(si, yi) : 0.f;
          zl[(rt * 16 + q * 4 + rr) * 96 + w * 16 + r] = (__bf16)(sr - si);
        }
      }
      __syncthreads();
      // copy-out: 64 rows x 48 dwords, coalesced
      {
        const uint32_t* zsrc = (const uint32_t*)zl;
        int cdw = t % 48, crow = t / 48;
        int rbase = m0 + h * 64;
#pragma unroll
        for (int it = 0; it < 8; it++) {
          int row = it * 8 + crow;
          uint32_t* dst = (uint32_t*)(Z + (size_t)(rbase + row) * CC + n0 + cb * 96);
          dst[cdw] = zsrc[row * 48 + cdw];
        }
      }
    }
  }
}

// ---------------- launch ----------------

extern "C" void kernel_launch(void* const* d_in, const int* in_sizes, int n_in,
                              void* d_out, int out_size, void* d_ws, size_t ws_size,
                              hipStream_t stream) {
  const float* x  = (const float*)d_in[0];
  const float* w1 = (const float*)d_in[1];
  const float* b1 = (const float*)d_in[2];
  const float* w2 = (const float*)d_in[3];
  const float* b2 = (const float*)d_in[4];
  float* out = (float*)d_out;

  char* ws = (char*)d_ws;
  size_t off = 0;
  auto alloc = [&](size_t bytes) {
    char* p = ws + off;
    off += (bytes + 255) & ~(size_t)255;
    return p;
  };
  __bf16* casb = (__bf16*)alloc((size_t)CC * CC * 2);        // 1.18 MB
  __bf16* w1f  = (__bf16*)alloc((size_t)8 * 36 * 64 * 8 * 2);
  __bf16* w2f  = (__bf16*)alloc((size_t)8 * 72 * 64 * 8 * 2);
  __bf16* xb   = (__bf16*)alloc((size_t)NTOT * 2);           // 50.3 MB
  __bf16* vv   = (__bf16*)alloc((size_t)NTOT * 2);           // 50.3 MB (Z)

  // all prep in one dispatch: cvt4 (24576 blks) | make_cas (2304) | pack_w1 (576) | pack_w2 (1152)
  prep_all<<<28608, 256, 0, stream>>>(x, xb, casb, w1, w1f, w2, w2f);

  // Z = softshrink-MLP(Xbf16 @ CAS), fused per (row-tile, channel-block-pair)
  fused3<<<1024, 384, 0, stream>>>(xb, casb, w1f, w2f, b1, b2, vv);
  // OUT = Z @ CAS / n_tot + X  (counted-vmcnt pipeline + coalesced epilogue)
  gemm_back<<<1536, 256, 0, stream>>>(vv, casb, out, x, 1.0f / 25165824.0f);
}